// Round 1
// baseline (111.780 us; speedup 1.0000x reference)
//
#include <hip/hip_runtime.h>
#include <math.h>

#define KS    7
#define PADW  3
#define NG    8
#define DD    8
#define RELC  4
#define H     56
#define W     56
#define TILE  16
#define PATCH 22                 // TILE + KS - 1
#define PATCH_N (PATCH * PATCH)  // 484

__global__ __launch_bounds__(256) void attn_fused(
    const float* __restrict__ x,
    const float* __restrict__ wq,
    const float* __restrict__ wk,
    const float* __restrict__ bk,
    const float* __restrict__ wv,
    const float* __restrict__ bv,
    const float* __restrict__ rel_x,
    const float* __restrict__ rel_y,
    float* __restrict__ out)
{
    __shared__ float xs[8 * PATCH_N];  // 8 group-input channels, 22x22 patch
    __shared__ float ks[PATCH_N];      // k_d patch
    __shared__ float vs[PATCH_N];      // v_d patch

    const int tid   = threadIdx.x;
    const int tileX = blockIdx.x;      // 0..3
    const int tileY = blockIdx.y;      // 0..3
    const int bc    = blockIdx.z;      // b*64 + c
    const int c     = bc & 63;
    const int g     = c >> 3;
    const int d     = c & 7;

    const int h0 = tileY * TILE;
    const int w0 = tileX * TILE;

    // ---- stage x patch: channels g*8..g*8+7, padded rows h0..h0+21 ----
    const float* xb = x + ((size_t)( (bc >> 6) * 64 + g * 8 )) * (H * W);
    for (int idx = tid; idx < 8 * PATCH_N; idx += 256) {
        int ch = idx / PATCH_N;
        int p  = idx - ch * PATCH_N;
        int ry = p / PATCH;
        int rx = p - ry * PATCH;
        int oy = h0 + ry - PADW;   // original-image row
        int ox = w0 + rx - PADW;
        float val = 0.f;
        if (oy >= 0 && oy < H && ox >= 0 && ox < W)
            val = xb[ch * (H * W) + oy * W + ox];
        xs[idx] = val;
    }

    // ---- block-uniform weights/bias/rel (broadcast via cache) ----
    float wqr[8], wkr[8], wvr[8];
#pragma unroll
    for (int i = 0; i < 8; ++i) {
        wqr[i] = wq[c * 8 + i];
        wkr[i] = wk[c * 8 + i];
        wvr[i] = wv[c * 8 + i];
    }
    const float bkc = bk[c];
    const float bvc = bv[c];
    const bool rel_is_row = (d < RELC);
    float r7[7];
#pragma unroll
    for (int i = 0; i < 7; ++i)
        r7[i] = rel_is_row ? rel_x[d * 7 + i] : rel_y[(d - RELC) * 7 + i];

    __syncthreads();

    // ---- k_d / v_d patch in LDS ----
    for (int p = tid; p < PATCH_N; p += 256) {
        float ka = bkc, va = bvc;
#pragma unroll
        for (int i = 0; i < 8; ++i) {
            float xv = xs[i * PATCH_N + p];
            ka += xv * wkr[i];
            va += xv * wvr[i];
        }
        ks[p] = ka;
        vs[p] = va;
    }
    __syncthreads();

    // ---- per-thread attention ----
    const int ty = tid >> 4;   // 0..15
    const int tx = tid & 15;
    const int h  = h0 + ty;
    const int w  = w0 + tx;

    // q_d from patch center (no bias for q)
    float qv = 0.f;
    const int cen = (ty + PADW) * PATCH + (tx + PADW);
#pragma unroll
    for (int i = 0; i < 8; ++i)
        qv += xs[i * PATCH_N + cen] * wqr[i];

    // logits in registers, track max
    float lg[49];
    float m = -1e30f;
#pragma unroll
    for (int i = 0; i < 7; ++i) {
#pragma unroll
        for (int j = 0; j < 7; ++j) {
            float r  = rel_is_row ? r7[i] : r7[j];
            float kk = ks[(ty + i) * PATCH + tx + j];
            float lv = qv * (kk + r);
            lg[i * 7 + j] = lv;
            m = fmaxf(m, lv);
        }
    }

    float l = 0.f, acc = 0.f;
#pragma unroll
    for (int i = 0; i < 7; ++i) {
#pragma unroll
        for (int j = 0; j < 7; ++j) {
            float e = __expf(lg[i * 7 + j] - m);
            l   += e;
            acc += e * vs[(ty + i) * PATCH + tx + j];
        }
    }

    if (h < H && w < W)
        out[((size_t)bc * H + h) * W + w] = acc / l;
}

extern "C" void kernel_launch(void* const* d_in, const int* in_sizes, int n_in,
                              void* d_out, int out_size, void* d_ws, size_t ws_size,
                              hipStream_t stream) {
    const float* x     = (const float*)d_in[0];
    const float* wq    = (const float*)d_in[1];
    const float* wk    = (const float*)d_in[2];
    const float* bk    = (const float*)d_in[3];
    const float* wv    = (const float*)d_in[4];
    const float* bv    = (const float*)d_in[5];
    const float* rel_x = (const float*)d_in[6];
    const float* rel_y = (const float*)d_in[7];

    dim3 grid(4, 4, 256);  // tilesX, tilesY, b*64+c
    attn_fused<<<grid, dim3(256), 0, stream>>>(
        x, wq, wk, bk, wv, bv, rel_x, rel_y, (float*)d_out);
}

// Round 2
// 106.246 us; speedup vs baseline: 1.0521x; 1.0521x over previous
//
#include <hip/hip_runtime.h>
#include <math.h>

#define KS    7
#define PADW  3
#define H     56
#define W     56
#define TILE  16
#define PATCH 22                 // TILE + KS - 1
#define PATCH_N (PATCH * PATCH)  // 484
#define PROW  24                 // padded row stride for ks/vs (bank-friendly)
#define PCHN  (PATCH * PROW)     // 528 floats per channel plane

__global__ __launch_bounds__(256, 2) void attn_fused(
    const float* __restrict__ x,
    const float* __restrict__ wq,
    const float* __restrict__ wk,
    const float* __restrict__ bk,
    const float* __restrict__ wv,
    const float* __restrict__ bv,
    const float* __restrict__ rel_x,
    const float* __restrict__ rel_y,
    float* __restrict__ out)
{
    __shared__ float xs [8 * PATCH_N];   // 8 input channels, 22x22 patch (flat)
    __shared__ float ksm[8 * PCHN];      // 8 output channels, 22 rows x stride 24
    __shared__ float vsm[8 * PCHN];

    const int tid   = threadIdx.x;
    const int tileX = blockIdx.x;        // 0..3
    const int tileY = blockIdx.y;        // 0..3
    const int bz    = blockIdx.z;        // b*8 + g
    const int b     = bz >> 3;
    const int g     = bz & 7;
    const int c0    = g * 8;

    const int h0 = tileY * TILE;
    const int w0 = tileX * TILE;

    // ---- stage x patch: input channels g*8..g*8+7, 22x22 halo ----
    const float* xb = x + ((size_t)(b * 64 + c0)) * (H * W);
    for (int idx = tid; idx < 8 * PATCH_N; idx += 256) {
        int ch = idx / PATCH_N;
        int p  = idx - ch * PATCH_N;
        int ry = p / PATCH;
        int rx = p - ry * PATCH;
        int oy = h0 + ry - PADW;
        int ox = w0 + rx - PADW;
        float val = 0.f;
        if (oy >= 0 && oy < H && ox >= 0 && ox < W)
            val = xb[ch * (H * W) + oy * W + ox];
        xs[idx] = val;
    }
    __syncthreads();

    // block-uniform weight bases (uniform indices -> scalar loads)
    const float* wqg = wq + g * 64;
    const float* wkg = wk + g * 64;
    const float* wvg = wv + g * 64;

    // ---- conv: all 8 k/v channels of the group, xv read once ----
    for (int p = tid; p < PATCH_N; p += 256) {
        int py = p / PATCH;
        int px = p - py * PATCH;
        int dst = py * PROW + px;
        float xv[8];
#pragma unroll
        for (int i = 0; i < 8; ++i) xv[i] = xs[i * PATCH_N + p];
#pragma unroll
        for (int dch = 0; dch < 8; ++dch) {
            float ka = bk[c0 + dch];
            float va = bv[c0 + dch];
#pragma unroll
            for (int i = 0; i < 8; ++i) {
                ka = fmaf(xv[i], wkg[dch * 8 + i], ka);
                va = fmaf(xv[i], wvg[dch * 8 + i], va);
            }
            ksm[dch * PCHN + dst] = ka;
            vsm[dch * PCHN + dst] = va;
        }
    }
    __syncthreads();

    // ---- attention: each thread = one pixel, loops over 8 channels ----
    const int ty = tid >> 4;             // 0..15
    const int tx = tid & 15;
    const int h  = h0 + ty;
    const int w  = w0 + tx;
    const bool valid = (h < H) && (w < W);

    // center x values (shared across the 8 channels' q dots)
    float xc[8];
    const int cen = (ty + PADW) * PATCH_N / PATCH_N; // dummy to keep pattern clear
    const int cidx = (ty + PADW) * PATCH + (tx + PADW);
#pragma unroll
    for (int i = 0; i < 8; ++i) xc[i] = xs[i * PATCH_N + cidx];

    const int base = ty * PROW + tx;

    for (int dch = 0; dch < 8; ++dch) {   // rolled: dch is block-uniform
        float qv = 0.f;
#pragma unroll
        for (int i = 0; i < 8; ++i) qv = fmaf(xc[i], wqg[dch * 8 + i], qv);

        // qv * r, 7 values; row-indexed for dch<4, col-indexed for dch>=4
        const bool rel_is_row = (dch < 4);
        float qvr[7];
#pragma unroll
        for (int i = 0; i < 7; ++i) {
            float r = rel_is_row ? rel_x[dch * 7 + i] : rel_y[(dch - 4) * 7 + i];
            qvr[i] = qv * r;
        }

        const float* kp = ksm + dch * PCHN + base;
        const float* vp = vsm + dch * PCHN + base;

        float l = 0.f, acc = 0.f;
#pragma unroll
        for (int i = 0; i < 7; ++i) {
#pragma unroll
            for (int j = 0; j < 7; ++j) {
                float addv = rel_is_row ? qvr[i] : qvr[j];
                float arg  = fmaf(qv, kp[i * PROW + j], addv);
                float e    = __expf(arg);
                l += e;
                acc = fmaf(e, vp[i * PROW + j], acc);
            }
        }

        if (valid)
            out[((size_t)(b * 64 + c0 + dch) * H + h) * W + w] = acc / l;
    }
}

extern "C" void kernel_launch(void* const* d_in, const int* in_sizes, int n_in,
                              void* d_out, int out_size, void* d_ws, size_t ws_size,
                              hipStream_t stream) {
    const float* x     = (const float*)d_in[0];
    const float* wq    = (const float*)d_in[1];
    const float* wk    = (const float*)d_in[2];
    const float* bk    = (const float*)d_in[3];
    const float* wv    = (const float*)d_in[4];
    const float* bv    = (const float*)d_in[5];
    const float* rel_x = (const float*)d_in[6];
    const float* rel_y = (const float*)d_in[7];

    dim3 grid(4, 4, 32);  // tilesX, tilesY, b*8+g
    attn_fused<<<grid, dim3(256), 0, stream>>>(
        x, wq, wk, bk, wv, bv, rel_x, rel_y, (float*)d_out);
}

// Round 3
// 82.334 us; speedup vs baseline: 1.3576x; 1.2904x over previous
//
#include <hip/hip_runtime.h>
#include <math.h>

#define KS    7
#define PADW  3
#define H     56
#define W     56
#define HW    (H * W)          // 3136
#define TILE  8
#define PATCH 14               // TILE + KS - 1
#define PROW  20               // padded LDS row stride: banks 2-way (free)
#define PCHN  (PATCH * PROW)   // 280 floats per channel plane

__global__ __launch_bounds__(256, 6) void attn_fused(
    const float* __restrict__ x,
    const float* __restrict__ wq,
    const float* __restrict__ wk,
    const float* __restrict__ bk,
    const float* __restrict__ wv,
    const float* __restrict__ bv,
    const float* __restrict__ rel_x,
    const float* __restrict__ rel_y,
    float* __restrict__ out)
{
    __shared__ float ksm[8 * PCHN];   // 8 output channels, 14 rows x stride 20
    __shared__ float vsm[8 * PCHN];

    const int tid  = threadIdx.x;
    const int tile = blockIdx.x;          // 0..48
    const int bz   = blockIdx.y;          // b*8 + g
    const int b    = bz >> 3;
    const int g    = bz & 7;
    const int c0   = g * 8;

    const int tileY = tile / 7;
    const int tileX = tile - tileY * 7;
    const int h0 = tileY * TILE;
    const int w0 = tileX * TILE;

    const float* wqg = wq + g * 64;       // block-uniform bases -> scalar loads
    const float* wkg = wk + g * 64;
    const float* wvg = wv + g * 64;
    const float* xg  = x + (size_t)(b * 64 + c0) * HW;

    // ---- conv phase: 196 patch positions, one thread each ----
    if (tid < PATCH * PATCH) {
        const int py = tid / PATCH;
        const int px = tid - py * PATCH;
        const int oy = h0 + py - PADW;
        const int ox = w0 + px - PADW;
        const bool in = (oy >= 0) & (oy < H) & (ox >= 0) & (ox < W);
        const float* xp = xg + oy * W + ox;
        float xv[8];
#pragma unroll
        for (int i = 0; i < 8; ++i)
            xv[i] = in ? xp[i * HW] : 0.f;
        const int dst = py * PROW + px;
#pragma unroll
        for (int dch = 0; dch < 8; ++dch) {
            float ka = bk[c0 + dch];
            float va = bv[c0 + dch];
#pragma unroll
            for (int i = 0; i < 8; ++i) {
                ka = fmaf(xv[i], wkg[dch * 8 + i], ka);
                va = fmaf(xv[i], wvg[dch * 8 + i], va);
            }
            ksm[dch * PCHN + dst] = ka;
            vsm[dch * PCHN + dst] = va;
        }
    }
    __syncthreads();

    // ---- attention: 512 (px,dch) tasks, 2 per thread; dch wave-uniform ----
    const int pix  = tid & 63;
    const int dsel = tid >> 6;            // 0..3, uniform per wave
    const int ty   = pix >> 3;
    const int tx   = pix & 7;
    const int h    = h0 + ty;
    const int w    = w0 + tx;

    // center x values (shared by both dch tasks of this thread)
    const float* xcp = xg + h * W + w;
    float xc[8];
#pragma unroll
    for (int i = 0; i < 8; ++i)
        xc[i] = xcp[i * HW];

    const int base = ty * PROW + tx;

#pragma unroll
    for (int half = 0; half < 2; ++half) {
        const int dch = half * 4 + dsel;  // uniform per wave

        float qv = 0.f;
#pragma unroll
        for (int i = 0; i < 8; ++i)
            qv = fmaf(xc[i], wqg[dch * 8 + i], qv);

        // half==0 -> dch<4: rel_x indexed by window row i
        // half==1 -> dch>=4: rel_y indexed by window col j
        float qvr[7];
#pragma unroll
        for (int i = 0; i < 7; ++i) {
            float r = (half == 0) ? rel_x[dch * 7 + i]
                                  : rel_y[(dch - 4) * 7 + i];
            qvr[i] = qv * r;
        }

        const float* kp = ksm + dch * PCHN + base;
        const float* vp = vsm + dch * PCHN + base;

        float l = 0.f, acc = 0.f;
#pragma unroll
        for (int i = 0; i < 7; ++i) {
#pragma unroll
            for (int j = 0; j < 7; ++j) {
                float addv = (half == 0) ? qvr[i] : qvr[j];
                float e = __expf(fmaf(qv, kp[i * PROW + j], addv));
                l += e;
                acc = fmaf(e, vp[i * PROW + j], acc);
            }
        }

        out[((size_t)(b * 64 + c0 + dch) * H + h) * W + w] = acc / l;
    }
}

extern "C" void kernel_launch(void* const* d_in, const int* in_sizes, int n_in,
                              void* d_out, int out_size, void* d_ws, size_t ws_size,
                              hipStream_t stream) {
    const float* x     = (const float*)d_in[0];
    const float* wq    = (const float*)d_in[1];
    const float* wk    = (const float*)d_in[2];
    const float* bk    = (const float*)d_in[3];
    const float* wv    = (const float*)d_in[4];
    const float* bv    = (const float*)d_in[5];
    const float* rel_x = (const float*)d_in[6];
    const float* rel_y = (const float*)d_in[7];

    dim3 grid(49, 32, 1);  // 7x7 tiles of 8x8, b*8+g
    attn_fused<<<grid, dim3(256), 0, stream>>>(
        x, wq, wk, bk, wv, bv, rel_x, rel_y, (float*)d_out);
}